// Round 10
// baseline (1654.713 us; speedup 1.0000x reference)
//
#include <hip/hip_runtime.h>
#include <hip/hip_cooperative_groups.h>
#include <math.h>

#define EPS_BN 1e-5

namespace {

namespace cg = cooperative_groups;

constexpr double CNT1 = 4096.0 * 1024.0;  // layer1 BN count: B*32*32
constexpr double CNT2 = 4096.0 * 256.0;   // layer2 BN count: B*16*16

// workspace layout (bytes). Required ws >= ~137 MiB.
constexpr size_t OFF_H1 = 0;            // [4096,256px,16ci] bf16 = 32 MiB
constexpr size_t OFF_Y1 = 67108864;     // [4096,1024px,8ch] f16 (fallback only)
constexpr size_t OFF_Y2 = 67108864;     // [4096,16,16,16] f32 = 64 MiB (aliases Y1)
constexpr size_t OFF_H2 = 0;            // [4096,2048] bf16 (reuses h1 after conv2)
constexpr size_t OFF_A1 = 33554432;     // [4096,512] bf16
constexpr size_t OFF_A2 = 41943040;     // [4096,512] f32
constexpr size_t OFF_ST = 134217728;    // BN stats: 96 slots x 64B
constexpr size_t OFF_WB1 = 134283264;   // fc1_w bf16 [512,2048] = 2 MiB
constexpr size_t OFF_WB2 = 136380416;   // fc2_w bf16 [512,512] = 0.5 MiB

#define STG(p, i) (p)[(size_t)(i) * 8]

typedef short bf16x8 __attribute__((ext_vector_type(8)));
typedef float f32x4 __attribute__((ext_vector_type(4)));
typedef _Float16 f16;
typedef _Float16 f16x8 __attribute__((ext_vector_type(8)));

__device__ __forceinline__ short f2bf(float f) {
  unsigned u = __float_as_uint(f);
  u = (u + 0x7fffu + ((u >> 16) & 1u)) >> 16;
  return (short)u;
}

__device__ __forceinline__ float wave_sum(float v) {
#pragma unroll
  for (int o = 32; o > 0; o >>= 1) v += __shfl_down(v, o, 64);
  return v;
}

template <int NV>
__device__ __forceinline__ void block_stats_atomic(const float* s, const float* q,
                                                   double* __restrict__ st) {
  __shared__ float red[4][NV * 2];
  const int lane = threadIdx.x & 63, wid = threadIdx.x >> 6;
#pragma unroll
  for (int c = 0; c < NV; ++c) {
    float sv = wave_sum(s[c]);
    float qv = wave_sum(q[c]);
    if (lane == 0) { red[wid][2 * c] = sv; red[wid][2 * c + 1] = qv; }
  }
  __syncthreads();
  if (threadIdx.x < NV * 2) {
    float v = red[0][threadIdx.x] + red[1][threadIdx.x] + red[2][threadIdx.x] +
              red[3][threadIdx.x];
    unsafeAtomicAdd(st + (size_t)threadIdx.x * 8, (double)v);
  }
}

__device__ __forceinline__ double stat_load(const double* p) {
  return __hip_atomic_load(p, __ATOMIC_RELAXED, __HIP_MEMORY_SCOPE_AGENT);
}

// ============ FUSED LAYER 1 (cooperative): conv1 + BN stats x2 + epilogue ====
// Grid MUST be 1024 x 256 (4 blocks/CU co-resident; <=128 VGPR via bounds).
// Each block: 4 images. y1 lives in registers (128 f16/thread) — no HBM y1.
// Thread = 4 consecutive px in row rr (R7 mapping): rr=tid>>3, c0=(tid&7)*4.
__global__ __launch_bounds__(256, 4) void k_layer1_coop(
    const float* __restrict__ x, const float* __restrict__ w1,
    const float* __restrict__ g1, const float* __restrict__ b1,
    const float* __restrict__ dsew, const float* __restrict__ bng,
    const float* __restrict__ bnb, double* __restrict__ st1,
    double* __restrict__ st2, short* __restrict__ h1) {
  __shared__ __align__(16) float xs[3 * 1224];  // 3 x 34 x 36 (stride 36)
  __shared__ __align__(16) float wk[216];
  __shared__ float cc[80];  // [0:8)=a1 [8:16)=c1 [16:48)=cS2 [48:80)=cO2
  const int tid = threadIdx.x;
  for (int i = tid; i < 3 * 1224; i += 256) xs[i] = 0.f;
  if (tid < 216) wk[(tid % 27) * 8 + tid / 27] = w1[tid];
  const int rr = tid >> 3, c0 = (tid & 7) * 4;
  const int n0 = blockIdx.x * 4;
  f16 yreg[4][32];  // [img][p*8+co]
  // ---- phase A: conv, 4 images, y kept in registers ----
#pragma unroll
  for (int img = 0; img < 4; ++img) {
    __syncthreads();
    {
      const float* xp = x + (size_t)(n0 + img) * 3072;
      for (int i = tid; i < 3072; i += 256) {
        int ci = i >> 10, r = (i >> 5) & 31, c = i & 31;
        xs[ci * 1224 + (r + 1) * 36 + (c + 1)] = xp[i];
      }
    }
    __syncthreads();
    float acc[4][8];
#pragma unroll
    for (int p = 0; p < 4; ++p)
#pragma unroll
      for (int co = 0; co < 8; ++co) acc[p][co] = 0.f;
#pragma unroll
    for (int ci = 0; ci < 3; ++ci)
#pragma unroll
      for (int dy = 0; dy < 3; ++dy) {
        const float* rowp = &xs[ci * 1224 + (rr + dy) * 36 + c0];
        float xw[6];
        *(float4*)&xw[0] = *(const float4*)rowp;
        *(float2*)&xw[4] = *(const float2*)(rowp + 4);
#pragma unroll
        for (int dx = 0; dx < 3; ++dx) {
          const int j = ci * 9 + dy * 3 + dx;
          float wv[8];
          *(float4*)&wv[0] = *(const float4*)&wk[j * 8];
          *(float4*)&wv[4] = *(const float4*)&wk[j * 8 + 4];
#pragma unroll
          for (int p = 0; p < 4; ++p)
#pragma unroll
            for (int co = 0; co < 8; ++co) acc[p][co] += xw[p + dx] * wv[co];
        }
      }
#pragma unroll
    for (int p = 0; p < 4; ++p)
#pragma unroll
      for (int co = 0; co < 8; ++co) yreg[img][p * 8 + co] = (f16)acc[p][co];
  }
  // ---- phase B: raw-y1 stats (on f16-rounded values, self-consistent) ----
  {
    float s[8], q[8];
#pragma unroll
    for (int c = 0; c < 8; ++c) { s[c] = 0.f; q[c] = 0.f; }
#pragma unroll
    for (int img = 0; img < 4; ++img)
#pragma unroll
      for (int p = 0; p < 4; ++p)
#pragma unroll
        for (int co = 0; co < 8; ++co) {
          float v = (float)yreg[img][p * 8 + co];
          s[co] += v; q[co] += v * v;
        }
    block_stats_atomic<8>(s, q, st1);
  }
  __threadfence();
  cg::this_grid().sync();
  // ---- phase C: xr1 stats from registers ----
  if (tid < 8) {
    double sd = stat_load(&STG(st1, 2 * tid));
    double qd = stat_load(&STG(st1, 2 * tid + 1));
    double md = sd / CNT1;
    float inv = (float)(1.0 / sqrt(qd / CNT1 - md * md + (double)EPS_BN));
    float a = inv * g1[tid];
    cc[tid] = a;
    cc[8 + tid] = b1[tid] - (float)md * a;
  }
  __syncthreads();
  {
    float a1r[8], c1r[8];
#pragma unroll
    for (int c = 0; c < 8; ++c) { a1r[c] = cc[c]; c1r[c] = cc[8 + c]; }
    float s[8], q[8];
#pragma unroll
    for (int c = 0; c < 8; ++c) { s[c] = 0.f; q[c] = 0.f; }
#pragma unroll
    for (int img = 0; img < 4; ++img)
#pragma unroll
      for (int p = 0; p < 4; ++p)
#pragma unroll
        for (int co = 0; co < 8; ++co) {
          float v = (float)yreg[img][p * 8 + co];
          float xr = fmaxf(v * a1r[co] + c1r[co], 0.f);
          s[co] += xr; q[co] += xr * xr;
        }
    block_stats_atomic<8>(s, q, st2);
  }
  __threadfence();
  cg::this_grid().sync();
  // ---- phase D: BN2 coefficients + fused epilogue + 2x2 maxpool ----
  if (tid < 32) {
    const int i = tid >> 1, g = tid & 1;
    double s2 = stat_load(&STG(st2, 2 * i));
    double q2 = stat_load(&STG(st2, 2 * i + 1));
    double mx = s2 / CNT1, vx = q2 / CNT1 - mx * mx;
    float w = dsew[i * 2 + g];
    double inv2 = 1.0 / sqrt((double)w * w * vx + (double)EPS_BN);
    cc[16 + tid] = (float)(w * inv2) * bng[tid];
    cc[48 + tid] = bnb[tid] - (float)(w * mx * inv2) * bng[tid];
  }
  __syncthreads();
#pragma unroll
  for (int img = 0; img < 4; ++img) {
    const int n = n0 + img;
    short hv0[16], hv1[16];
#pragma unroll
    for (int i = 0; i < 8; ++i) {
      float a = cc[i], c = cc[8 + i];
      float xr0 = fmaxf((float)yreg[img][0 * 8 + i] * a + c, 0.f);
      float xr1 = fmaxf((float)yreg[img][1 * 8 + i] * a + c, 0.f);
      float xr2 = fmaxf((float)yreg[img][2 * 8 + i] * a + c, 0.f);
      float xr3 = fmaxf((float)yreg[img][3 * 8 + i] * a + c, 0.f);
#pragma unroll
      for (int g = 0; g < 2; ++g) {
        const int ch = 2 * i + g;
        float sc = cc[16 + ch], of = cc[48 + ch];
        float v0 = fmaxf(xr0 * sc + of, 0.f);
        float v1 = fmaxf(xr1 * sc + of, 0.f);
        float v2 = fmaxf(xr2 * sc + of, 0.f);
        float v3 = fmaxf(xr3 * sc + of, 0.f);
        float h0 = fmaxf(v0, v1);   // cols c0,c0+1
        float h1v = fmaxf(v2, v3);  // cols c0+2,c0+3
        float p0 = __shfl_xor(h0, 8, 64);   // row partner (rr^1)
        float p1 = __shfl_xor(h1v, 8, 64);
        hv0[ch] = f2bf(fmaxf(h0, p0));
        hv1[ch] = f2bf(fmaxf(h1v, p1));
      }
    }
    if ((rr & 1) == 0) {
      const int py = rr >> 1, ox0 = c0 >> 1;
      uint4* d0 = (uint4*)&h1[((size_t)n * 256 + py * 16 + ox0) * 16];
      d0[0] = ((uint4*)hv0)[0];
      d0[1] = ((uint4*)hv0)[1];
      uint4* d1 = (uint4*)&h1[((size_t)n * 256 + py * 16 + ox0 + 1) * 16];
      d1[0] = ((uint4*)hv1)[0];
      d1[1] = ((uint4*)hv1)[1];
    }
  }
}

// ================== FALLBACK PATH (exact R7 kernels) =========================
__global__ __launch_bounds__(256) void k_conv1_y1(
    const float* __restrict__ x, const float* __restrict__ w1,
    f16* __restrict__ y1, double* __restrict__ st1) {
  __shared__ __align__(16) float xs[3 * 1224];
  __shared__ __align__(16) float wk[216];
  const int tid = threadIdx.x;
  for (int i = tid; i < 3 * 1224; i += 256) xs[i] = 0.f;
  if (tid < 216) wk[(tid % 27) * 8 + tid / 27] = w1[tid];
  const int rr = tid >> 3, c0 = (tid & 7) * 4;
  const int n0 = blockIdx.x * 2;
  float s[8], q[8];
#pragma unroll
  for (int c = 0; c < 8; ++c) { s[c] = 0.f; q[c] = 0.f; }
  for (int img = 0; img < 2; ++img) {
    __syncthreads();
    {
      const float* xp = x + (size_t)(n0 + img) * 3072;
      for (int i = tid; i < 3072; i += 256) {
        int ci = i >> 10, r = (i >> 5) & 31, c = i & 31;
        xs[ci * 1224 + (r + 1) * 36 + (c + 1)] = xp[i];
      }
    }
    __syncthreads();
    float acc[4][8];
#pragma unroll
    for (int p = 0; p < 4; ++p)
#pragma unroll
      for (int co = 0; co < 8; ++co) acc[p][co] = 0.f;
#pragma unroll
    for (int ci = 0; ci < 3; ++ci)
#pragma unroll
      for (int dy = 0; dy < 3; ++dy) {
        const float* rowp = &xs[ci * 1224 + (rr + dy) * 36 + c0];
        float xw[6];
        *(float4*)&xw[0] = *(const float4*)rowp;
        *(float2*)&xw[4] = *(const float2*)(rowp + 4);
#pragma unroll
        for (int dx = 0; dx < 3; ++dx) {
          const int j = ci * 9 + dy * 3 + dx;
          float wv[8];
          *(float4*)&wv[0] = *(const float4*)&wk[j * 8];
          *(float4*)&wv[4] = *(const float4*)&wk[j * 8 + 4];
#pragma unroll
          for (int p = 0; p < 4; ++p)
#pragma unroll
            for (int co = 0; co < 8; ++co) acc[p][co] += xw[p + dx] * wv[co];
        }
      }
    f16* yp = &y1[((size_t)(n0 + img) * 1024 + rr * 32 + c0) * 8];
#pragma unroll
    for (int p = 0; p < 4; ++p) {
      f16 hv8[8];
#pragma unroll
      for (int co = 0; co < 8; ++co) {
        float v = acc[p][co];
        s[co] += v; q[co] += v * v;
        hv8[co] = (f16)v;
      }
      *(uint4*)&yp[p * 8] = *(uint4*)hv8;
    }
  }
  block_stats_atomic<8>(s, q, st1);
}

__global__ __launch_bounds__(256) void k_xr1_stats(
    const f16* __restrict__ y1, const float* __restrict__ g1,
    const float* __restrict__ b1, const double* __restrict__ st1,
    double* __restrict__ st2) {
  float a1[8], c1[8];
#pragma unroll
  for (int c = 0; c < 8; ++c) {
    double sd = STG(st1, 2 * c), qd = STG(st1, 2 * c + 1);
    double md = sd / CNT1;
    float inv = (float)(1.0 / sqrt(qd / CNT1 - md * md + (double)EPS_BN));
    a1[c] = inv * g1[c];
    c1[c] = b1[c] - (float)md * a1[c];
  }
  const size_t base = (size_t)blockIdx.x * 4096 + threadIdx.x;
  float s[8], q[8];
#pragma unroll
  for (int c = 0; c < 8; ++c) { s[c] = 0.f; q[c] = 0.f; }
#pragma unroll
  for (int k = 0; k < 16; ++k) {
    f16x8 v = *(const f16x8*)&y1[(base + (size_t)k * 256) * 8];
#pragma unroll
    for (int c = 0; c < 8; ++c) {
      float xr = fmaxf((float)v[c] * a1[c] + c1[c], 0.f);
      s[c] += xr; q[c] += xr * xr;
    }
  }
  block_stats_atomic<8>(s, q, st2);
}

__global__ __launch_bounds__(256) void k_l1_out(
    const f16* __restrict__ y1, const float* __restrict__ g1,
    const float* __restrict__ b1, const float* __restrict__ dsew,
    const float* __restrict__ bng, const float* __restrict__ bnb,
    const double* __restrict__ st1, const double* __restrict__ st2,
    short* __restrict__ h1) {
  __shared__ float cA1[8], cC1[8], cS2[16], cO2[16];
  const int tid = threadIdx.x;
  if (tid < 16) {
    const int i = tid >> 1, g = tid & 1;
    double sd = STG(st1, 2 * i), qd = STG(st1, 2 * i + 1);
    double md = sd / CNT1;
    float inv1 = (float)(1.0 / sqrt(qd / CNT1 - md * md + (double)EPS_BN));
    float a1 = inv1 * g1[i];
    if (g == 0) { cA1[i] = a1; cC1[i] = b1[i] - (float)md * a1; }
    double s2 = STG(st2, 2 * i), q2 = STG(st2, 2 * i + 1);
    double mx = s2 / CNT1, vx = q2 / CNT1 - mx * mx;
    float w = dsew[i * 2 + g];
    double inv2 = 1.0 / sqrt((double)w * w * vx + (double)EPS_BN);
    cS2[tid] = (float)(w * inv2) * bng[tid];
    cO2[tid] = bnb[tid] - (float)(w * mx * inv2) * bng[tid];
  }
  __syncthreads();
  const int sub = tid >> 6, lane = tid & 63;
  const int n = blockIdx.x * 4 + sub;
#pragma unroll
  for (int w = 0; w < 4; ++w) {
    const int opx = w * 64 + lane, oy = opx >> 4, ox = opx & 15;
    const size_t pbase = ((size_t)n * 1024 + (size_t)(2 * oy) * 32 + 2 * ox) * 8;
    f16x8 vA = *(const f16x8*)&y1[pbase];
    f16x8 vB = *(const f16x8*)&y1[pbase + 8];
    f16x8 vC = *(const f16x8*)&y1[pbase + 256];
    f16x8 vD = *(const f16x8*)&y1[pbase + 264];
    short hv[16];
#pragma unroll
    for (int i = 0; i < 8; ++i) {
      float a1 = cA1[i], c1 = cC1[i];
      float xr0 = fmaxf((float)vA[i] * a1 + c1, 0.f);
      float xr1 = fmaxf((float)vB[i] * a1 + c1, 0.f);
      float xr2 = fmaxf((float)vC[i] * a1 + c1, 0.f);
      float xr3 = fmaxf((float)vD[i] * a1 + c1, 0.f);
#pragma unroll
      for (int g = 0; g < 2; ++g) {
        const int c = 2 * i + g;
        float sc = cS2[c], of = cO2[c];
        float r0 = fmaxf(xr0 * sc + of, 0.f);
        float r1 = fmaxf(xr1 * sc + of, 0.f);
        float r2 = fmaxf(xr2 * sc + of, 0.f);
        float r3 = fmaxf(xr3 * sc + of, 0.f);
        hv[c] = f2bf(fmaxf(fmaxf(r0, r1), fmaxf(r2, r3)));
      }
    }
    uint4* dst = (uint4*)&h1[((size_t)n * 256 + opx) * 16];
    dst[0] = ((uint4*)hv)[0];
    dst[1] = ((uint4*)hv)[1];
  }
}

// ---------------- layer 2 conv via MFMA (R7 form: grid 512, 8 img) ----------
__global__ __launch_bounds__(256) void k_conv2_mfma(
    const short* __restrict__ h1, const float* __restrict__ w2,
    float* __restrict__ y2, double* __restrict__ st3) {
  __shared__ short smem[4 * 5184 + 10 * 256];
  __shared__ float red[4][32];
  short* hs = smem;
  short* wt = smem + 4 * 5184;
  const int tid = threadIdx.x, wid = tid >> 6, lane = tid & 63;
  for (int i = tid; i < (4 * 5184 + 10 * 256) / 2; i += 256) ((int*)smem)[i] = 0;
  __syncthreads();
  for (int i = tid; i < 2304; i += 256) {
    const int s = i >> 8, co = (i >> 4) & 15, ci = i & 15;
    wt[i] = f2bf(w2[(co * 16 + ci) * 9 + s]);
  }
  const int c = lane & 15, quad = lane >> 4;
  const int ci0 = (quad & 1) * 8;
  int aoff[5];
#pragma unroll
  for (int p = 0; p < 5; ++p) {
    int s = 2 * p + (quad >> 1);
    if (s > 8) s = 8;
    const int dy = s / 3, dx = s % 3;
    aoff[p] = (dy * 18 + (c + dx)) * 16 + ci0;
  }
  float ssum = 0.f, qsum = 0.f;
  for (int it = 0; it < 2; ++it) {
    __syncthreads();
    {
      const uint4* src =
          (const uint4*)(h1 + ((size_t)blockIdx.x * 8 + it * 4) * 4096);
      for (int ch = tid; ch < 2048; ch += 256) {
        const int im = ch >> 9, j = ch & 511, px = j >> 1, half = j & 1;
        const int r = px >> 4, cc2 = px & 15;
        *(uint4*)&hs[im * 5184 + ((r + 1) * 18 + (cc2 + 1)) * 16 + half * 8] =
            src[ch];
      }
    }
    __syncthreads();
    bf16x8 bf[5];
#pragma unroll
    for (int p = 0; p < 5; ++p) {
      const int s = 2 * p + (quad >> 1);
      bf[p] = *(const bf16x8*)&wt[s * 256 + c * 16 + ci0];
    }
    const short* hbase = hs + wid * 5184;
    const int img = blockIdx.x * 8 + it * 4 + wid;
    float* yp = y2 + ((size_t)img * 16 + c) * 256 + quad * 4;
    for (int r = 0; r < 16; ++r) {
      f32x4 acc = {0.f, 0.f, 0.f, 0.f};
#pragma unroll
      for (int p = 0; p < 5; ++p) {
        bf16x8 a = *(const bf16x8*)&hbase[r * 288 + aoff[p]];
        acc = __builtin_amdgcn_mfma_f32_16x16x32_bf16(a, bf[p], acc, 0, 0, 0);
      }
      *(float4*)&yp[r * 16] = *(float4*)&acc;
#pragma unroll
      for (int g = 0; g < 4; ++g) { float v = acc[g]; ssum += v; qsum += v * v; }
    }
  }
  ssum += __shfl_down(ssum, 32, 64); ssum += __shfl_down(ssum, 16, 64);
  qsum += __shfl_down(qsum, 32, 64); qsum += __shfl_down(qsum, 16, 64);
  if (lane < 16) { red[wid][lane] = ssum; red[wid][16 + lane] = qsum; }
  __syncthreads();
  if (tid < 32) {
    const int cc2 = tid & 15, isq = tid >> 4;
    float v = red[0][isq * 16 + cc2] + red[1][isq * 16 + cc2] +
              red[2][isq * 16 + cc2] + red[3][isq * 16 + cc2];
    unsafeAtomicAdd(st3 + (size_t)(2 * cc2 + isq) * 8, (double)v);
  }
}

__global__ __launch_bounds__(256) void k_xr2_stats(
    const float* __restrict__ y2, const float* __restrict__ g2,
    const float* __restrict__ b2, const double* __restrict__ st3,
    double* __restrict__ st4) {
  const int c = blockIdx.x & 15, n0 = (blockIdx.x >> 4) << 4;
  double sd = STG(st3, 2 * c), qd = STG(st3, 2 * c + 1);
  double md = sd / CNT2;
  float m = (float)md;
  float inv = (float)(1.0 / sqrt(qd / CNT2 - md * md + (double)EPS_BN));
  float gg = g2[c], bb = b2[c];
  float s = 0.f, q = 0.f;
#pragma unroll
  for (int k = 0; k < 16; ++k) {
    float v = y2[((size_t)(n0 + k) * 16 + c) * 256 + threadIdx.x];
    float xr = fmaxf((v - m) * inv * gg + bb, 0.f);
    s += xr; q += xr * xr;
  }
  block_stats_atomic<1>(&s, &q, st4 + (size_t)(2 * c) * 8);
}

__global__ __launch_bounds__(256) void k_l2_out(
    const float* __restrict__ y2, const float* __restrict__ g2,
    const float* __restrict__ b2, const float* __restrict__ dsew,
    const float* __restrict__ bng, const float* __restrict__ bnb,
    const double* __restrict__ st3, const double* __restrict__ st4,
    short* __restrict__ h2) {
  __shared__ float cS3[16], cO3[16], cS4[32], cO4[32];
  const int tid = threadIdx.x;
  if (tid < 32) {
    const int i = tid >> 1, g = tid & 1;
    double sd = STG(st3, 2 * i), qd = STG(st3, 2 * i + 1);
    double md = sd / CNT2;
    float inv3 = (float)(1.0 / sqrt(qd / CNT2 - md * md + (double)EPS_BN));
    float a3 = inv3 * g2[i];
    if (g == 0) { cS3[i] = a3; cO3[i] = b2[i] - (float)md * a3; }
    double s4 = STG(st4, 2 * i), q4 = STG(st4, 2 * i + 1);
    double mx = s4 / CNT2, vx = q4 / CNT2 - mx * mx;
    float w = dsew[2 * i + g];
    double inv4 = 1.0 / sqrt((double)w * w * vx + (double)EPS_BN);
    cS4[tid] = (float)(w * inv4) * bng[tid];
    cO4[tid] = bnb[tid] - (float)(w * mx * inv4) * bng[tid];
  }
  __syncthreads();
  const int sub = tid >> 6, lane = tid & 63;
  const int n = blockIdx.x * 4 + sub;
  const int px = lane & 7, py = lane >> 3;
#pragma unroll
  for (int i = 0; i < 16; ++i) {
    const size_t base = ((size_t)n * 16 + i) * 256;
    float2 v01 = *(const float2*)&y2[base + (2 * py) * 16 + 2 * px];
    float2 v23 = *(const float2*)&y2[base + (2 * py + 1) * 16 + 2 * px];
    float a3 = cS3[i], c3 = cO3[i];
    float xr0 = fmaxf(v01.x * a3 + c3, 0.f);
    float xr1 = fmaxf(v01.y * a3 + c3, 0.f);
    float xr2 = fmaxf(v23.x * a3 + c3, 0.f);
    float xr3 = fmaxf(v23.y * a3 + c3, 0.f);
#pragma unroll
    for (int g = 0; g < 2; ++g) {
      const int c = 2 * i + g;
      float sc = cS4[c], of = cO4[c];
      float r0 = fmaxf(xr0 * sc + of, 0.f);
      float r1 = fmaxf(xr1 * sc + of, 0.f);
      float r2 = fmaxf(xr2 * sc + of, 0.f);
      float r3 = fmaxf(xr3 * sc + of, 0.f);
      h2[(size_t)n * 2048 + c * 64 + py * 8 + px] =
          f2bf(fmaxf(fmaxf(r0, r1), fmaxf(r2, r3)));
    }
  }
}

// cast fc1_w/fc2_w to bf16 (vectorized) + zero stat slots
__global__ __launch_bounds__(256) void k_cast_w(const float* __restrict__ w1,
                                                const float* __restrict__ w2,
                                                short* __restrict__ o1,
                                                short* __restrict__ o2,
                                                double* __restrict__ st) {
  const int i4 = blockIdx.x * 256 + threadIdx.x;
  if (blockIdx.x == 0) {
    for (int k = threadIdx.x; k < 768; k += 256) st[k] = 0.0;
  }
  if (i4 < 262144) {
    float4 v = ((const float4*)w1)[i4];
    short h[4] = {f2bf(v.x), f2bf(v.y), f2bf(v.z), f2bf(v.w)};
    ((uint2*)o1)[i4] = *(uint2*)h;
  } else if (i4 < 327680) {
    const int j = i4 - 262144;
    float4 v = ((const float4*)w2)[j];
    short h[4] = {f2bf(v.x), f2bf(v.y), f2bf(v.z), f2bf(v.w)};
    ((uint2*)o2)[j] = *(uint2*)h;
  }
}

// ------------- FC via MFMA: C[M,512] = act(A[M,K]bf16 @ W[512,K]bf16^T + b) --
template <int K, int RELU, int OUT_BF16>
__global__ __launch_bounds__(256) void k_fc_mfma(
    const short* __restrict__ A, const short* __restrict__ W,
    const float* __restrict__ bias, void* __restrict__ Cv) {
  const int wv = threadIdx.x >> 6, lane = threadIdx.x & 63;
  const int bm = blockIdx.y * 64;
  const int bn = blockIdx.x * 64 + wv * 16;
  const int cl = lane & 15, quad = lane >> 4;
  const short* ap = A + (size_t)(bm + cl) * K + quad * 8;
  const short* bp = W + (size_t)(bn + cl) * K + quad * 8;
  f32x4 acc0 = {0.f, 0.f, 0.f, 0.f}, acc1 = acc0, acc2 = acc0, acc3 = acc0;
#pragma unroll 4
  for (int k0 = 0; k0 < K; k0 += 32) {
    bf16x8 b = *(const bf16x8*)bp;
    bf16x8 a0 = *(const bf16x8*)ap;
    bf16x8 a1 = *(const bf16x8*)(ap + (size_t)16 * K);
    bf16x8 a2 = *(const bf16x8*)(ap + (size_t)32 * K);
    bf16x8 a3 = *(const bf16x8*)(ap + (size_t)48 * K);
    ap += 32; bp += 32;
    acc0 = __builtin_amdgcn_mfma_f32_16x16x32_bf16(a0, b, acc0, 0, 0, 0);
    acc1 = __builtin_amdgcn_mfma_f32_16x16x32_bf16(a1, b, acc1, 0, 0, 0);
    acc2 = __builtin_amdgcn_mfma_f32_16x16x32_bf16(a2, b, acc2, 0, 0, 0);
    acc3 = __builtin_amdgcn_mfma_f32_16x16x32_bf16(a3, b, acc3, 0, 0, 0);
  }
  const float bia = bias[bn + cl];
  f32x4 av[4] = {acc0, acc1, acc2, acc3};
#pragma unroll
  for (int rt = 0; rt < 4; ++rt) {
#pragma unroll
    for (int r = 0; r < 4; ++r) {
      const int row = bm + rt * 16 + quad * 4 + r;
      float v = av[rt][r] + bia;
      if (RELU) v = fmaxf(v, 0.f);
      if (OUT_BF16)
        ((short*)Cv)[(size_t)row * 512 + bn + cl] = f2bf(v);
      else
        ((float*)Cv)[(size_t)row * 512 + bn + cl] = v;
    }
  }
}

// fc3: one wave per row, N=10, K=512, fp32
__global__ __launch_bounds__(256) void k_fc3(const float* __restrict__ A,
                                             const float* __restrict__ W,
                                             const float* __restrict__ b,
                                             float* __restrict__ out) {
  const int wid = threadIdx.x >> 6, lane = threadIdx.x & 63;
  const int row = blockIdx.x * 4 + wid;
  float p[10];
#pragma unroll
  for (int o = 0; o < 10; ++o) p[o] = 0.f;
  const float* a = A + (size_t)row * 512;
#pragma unroll
  for (int jj = 0; jj < 8; ++jj) {
    const int j = lane + jj * 64;
    float av = a[j];
#pragma unroll
    for (int o = 0; o < 10; ++o) p[o] += av * W[o * 512 + j];
  }
#pragma unroll
  for (int o = 0; o < 10; ++o) p[o] = wave_sum(p[o]);
  if (lane == 0) {
#pragma unroll
    for (int o = 0; o < 10; ++o) out[(size_t)row * 10 + o] = p[o] + b[o];
  }
}

}  // namespace

extern "C" void kernel_launch(void* const* d_in, const int* in_sizes, int n_in,
                              void* d_out, int out_size, void* d_ws,
                              size_t ws_size, hipStream_t stream) {
  const float* x      = (const float*)d_in[0];
  const float* dfe1_w = (const float*)d_in[1];
  const float* dse1_g = (const float*)d_in[2];
  const float* dse1_b = (const float*)d_in[3];
  const float* dse1_w = (const float*)d_in[4];
  const float* bn1_g  = (const float*)d_in[5];
  const float* bn1_b  = (const float*)d_in[6];
  const float* dfe2_w = (const float*)d_in[7];
  const float* dse2_g = (const float*)d_in[8];
  const float* dse2_b = (const float*)d_in[9];
  const float* dse2_w = (const float*)d_in[10];
  const float* bn2_g  = (const float*)d_in[11];
  const float* bn2_b  = (const float*)d_in[12];
  const float* fc1_w  = (const float*)d_in[13];
  const float* fc1_b  = (const float*)d_in[14];
  const float* fc2_w  = (const float*)d_in[15];
  const float* fc2_b  = (const float*)d_in[16];
  const float* fc3_w  = (const float*)d_in[17];
  const float* fc3_b  = (const float*)d_in[18];
  float* out = (float*)d_out;
  char* ws = (char*)d_ws;
  short* h1 = (short*)(ws + OFF_H1);
  f16* y1 = (f16*)(ws + OFF_Y1);
  float* y2 = (float*)(ws + OFF_Y2);
  short* h2 = (short*)(ws + OFF_H2);
  short* a1 = (short*)(ws + OFF_A1);
  float* a2 = (float*)(ws + OFF_A2);
  short* wb1 = (short*)(ws + OFF_WB1);
  short* wb2 = (short*)(ws + OFF_WB2);
  double* st = (double*)(ws + OFF_ST);
  double* ST1 = st;
  double* ST2 = st + (size_t)16 * 8;
  double* ST3 = st + (size_t)32 * 8;
  double* ST4 = st + (size_t)64 * 8;

  k_cast_w<<<1280, 256, 0, stream>>>(fc1_w, fc2_w, wb1, wb2, st);

  // fused layer-1 (cooperative). On any launch failure, fall back to the
  // proven three-kernel path — identical numerics either way.
  {
    void* args[] = {(void*)&x,      (void*)&dfe1_w, (void*)&dse1_g,
                    (void*)&dse1_b, (void*)&dse1_w, (void*)&bn1_g,
                    (void*)&bn1_b,  (void*)&ST1,    (void*)&ST2, (void*)&h1};
    hipError_t e = hipLaunchCooperativeKernel((const void*)k_layer1_coop,
                                              dim3(1024), dim3(256), args, 0,
                                              stream);
    if (e != hipSuccess) {
      (void)hipGetLastError();  // clear sticky error
      k_conv1_y1<<<2048, 256, 0, stream>>>(x, dfe1_w, y1, ST1);
      k_xr1_stats<<<1024, 256, 0, stream>>>(y1, dse1_g, dse1_b, ST1, ST2);
      k_l1_out<<<1024, 256, 0, stream>>>(y1, dse1_g, dse1_b, dse1_w, bn1_g,
                                         bn1_b, ST1, ST2, h1);
    }
  }

  k_conv2_mfma<<<512, 256, 0, stream>>>(h1, dfe2_w, y2, ST3);
  k_xr2_stats<<<4096, 256, 0, stream>>>(y2, dse2_g, dse2_b, ST3, ST4);
  k_l2_out<<<1024, 256, 0, stream>>>(y2, dse2_g, dse2_b, dse2_w, bn2_g, bn2_b,
                                     ST3, ST4, h2);
  k_fc_mfma<2048, 1, 1><<<dim3(8, 64), 256, 0, stream>>>(h2, wb1, fc1_b, a1);
  k_fc_mfma<512, 1, 0><<<dim3(8, 64), 256, 0, stream>>>(a1, wb2, fc2_b, a2);
  k_fc3<<<1024, 256, 0, stream>>>(a2, fc3_w, fc3_b, out);
}

// Round 11
// 394.513 us; speedup vs baseline: 4.1943x; 4.1943x over previous
//
#include <hip/hip_runtime.h>
#include <math.h>

#define EPS_BN 1e-5

namespace {

constexpr double CNT1 = 4096.0 * 1024.0;  // layer1 BN count: B*32*32
constexpr double CNT2 = 4096.0 * 256.0;   // layer2 BN count: B*16*16

// workspace layout (bytes). Required ws >= ~137 MiB.
constexpr size_t OFF_H1 = 0;            // [4096,256px,16ci] bf16 = 32 MiB
constexpr size_t OFF_Y1 = 67108864;     // [4096,1024px,8ch] f16 = 64 MiB (dies after l1_out)
constexpr size_t OFF_Y2 = 67108864;     // [4096,16,16,16] f32 = 64 MiB (aliases Y1)
constexpr size_t OFF_H2 = 0;            // [4096,2048] bf16 (reuses h1 after conv2)
constexpr size_t OFF_A1 = 33554432;     // [4096,512] bf16
constexpr size_t OFF_A2 = 41943040;     // [4096,512] f32
constexpr size_t OFF_ST = 134217728;    // BN stats: 96 slots x 64B
constexpr size_t OFF_WB1 = 134283264;   // fc1_w bf16 [512,2048] = 2 MiB
constexpr size_t OFF_WB2 = 136380416;   // fc2_w bf16 [512,512] = 0.5 MiB

#define STG(p, i) (p)[(size_t)(i) * 8]

typedef short bf16x8 __attribute__((ext_vector_type(8)));
typedef float f32x4 __attribute__((ext_vector_type(4)));
typedef _Float16 f16;
typedef _Float16 f16x8 __attribute__((ext_vector_type(8)));

__device__ __forceinline__ short f2bf(float f) {
  unsigned u = __float_as_uint(f);
  u = (u + 0x7fffu + ((u >> 16) & 1u)) >> 16;
  return (short)u;
}

__device__ __forceinline__ float wave_sum(float v) {
#pragma unroll
  for (int o = 32; o > 0; o >>= 1) v += __shfl_down(v, o, 64);
  return v;
}

template <int NV>
__device__ __forceinline__ void block_stats_atomic(const float* s, const float* q,
                                                   double* __restrict__ st) {
  __shared__ float red[4][NV * 2];
  const int lane = threadIdx.x & 63, wid = threadIdx.x >> 6;
#pragma unroll
  for (int c = 0; c < NV; ++c) {
    float sv = wave_sum(s[c]);
    float qv = wave_sum(q[c]);
    if (lane == 0) { red[wid][2 * c] = sv; red[wid][2 * c + 1] = qv; }
  }
  __syncthreads();
  if (threadIdx.x < NV * 2) {
    float v = red[0][threadIdx.x] + red[1][threadIdx.x] + red[2][threadIdx.x] +
              red[3][threadIdx.x];
    unsafeAtomicAdd(st + (size_t)threadIdx.x * 8, (double)v);
  }
}

// ---------------- layer 1: conv 3x3, 3->8, on 32x32, pad 1 -------------------
// R7 mapping (thread = 4 consecutive px in row rr; rr=tid>>3, c0=(tid&7)*4;
// LDS row stride 36 for 16B-aligned reads) + software-pipelined staging:
// double-buffered x in LDS; while computing image i from buf, the global loads
// for image i+1 fill buf^1. ONE acc set live (unlike R6's dual-compute which
// blew VGPR to 172). One barrier per image. 4 images/block, grid 1024.
// Writes y1 f16 NHWC [n][1024px][8ch] + raw-y1 stats.
__global__ __launch_bounds__(256) void k_conv1_y1(
    const float* __restrict__ x, const float* __restrict__ w1,
    f16* __restrict__ y1, double* __restrict__ st1) {
  __shared__ __align__(16) float xs[2][3 * 1224];  // 2 x (3 x 34 x 36)
  __shared__ __align__(16) float wk[216];
  const int tid = threadIdx.x;
  for (int i = tid; i < 2 * 3 * 1224; i += 256) (&xs[0][0])[i] = 0.f;
  if (tid < 216) wk[(tid % 27) * 8 + tid / 27] = w1[tid];
  const int rr = tid >> 3, c0 = (tid & 7) * 4;
  const int n0 = blockIdx.x * 4;
  float s[8], q[8];
#pragma unroll
  for (int c = 0; c < 8; ++c) { s[c] = 0.f; q[c] = 0.f; }
  __syncthreads();  // zero-init + wk visible
  {  // prologue: stage image 0 into buf 0
    const float* xp = x + (size_t)n0 * 3072;
    for (int i = tid; i < 3072; i += 256) {
      int ci = i >> 10, r = (i >> 5) & 31, c = i & 31;
      xs[0][ci * 1224 + (r + 1) * 36 + (c + 1)] = xp[i];
    }
  }
#pragma unroll 1
  for (int img = 0; img < 4; ++img) {
    const int buf = img & 1;
    __syncthreads();  // buf staged; previous compute on buf^1 finished
    if (img + 1 < 4) {  // stage next image into the other buffer (overlaps)
      const float* xp = x + (size_t)(n0 + img + 1) * 3072;
      for (int i = tid; i < 3072; i += 256) {
        int ci = i >> 10, r = (i >> 5) & 31, c = i & 31;
        xs[buf ^ 1][ci * 1224 + (r + 1) * 36 + (c + 1)] = xp[i];
      }
    }
    float acc[4][8];
#pragma unroll
    for (int p = 0; p < 4; ++p)
#pragma unroll
      for (int co = 0; co < 8; ++co) acc[p][co] = 0.f;
#pragma unroll
    for (int ci = 0; ci < 3; ++ci)
#pragma unroll
      for (int dy = 0; dy < 3; ++dy) {
        const float* rowp = &xs[buf][ci * 1224 + (rr + dy) * 36 + c0];
        float xw[6];
        *(float4*)&xw[0] = *(const float4*)rowp;
        *(float2*)&xw[4] = *(const float2*)(rowp + 4);
#pragma unroll
        for (int dx = 0; dx < 3; ++dx) {
          const int j = ci * 9 + dy * 3 + dx;
          float wv[8];
          *(float4*)&wv[0] = *(const float4*)&wk[j * 8];
          *(float4*)&wv[4] = *(const float4*)&wk[j * 8 + 4];
#pragma unroll
          for (int p = 0; p < 4; ++p)
#pragma unroll
            for (int co = 0; co < 8; ++co) acc[p][co] += xw[p + dx] * wv[co];
        }
      }
    f16* yp = &y1[((size_t)(n0 + img) * 1024 + rr * 32 + c0) * 8];
#pragma unroll
    for (int p = 0; p < 4; ++p) {
      f16 hv8[8];
#pragma unroll
      for (int co = 0; co < 8; ++co) {
        float v = acc[p][co];
        s[co] += v; q[co] += v * v;
        hv8[co] = (f16)v;
      }
      *(uint4*)&yp[p * 8] = *(uint4*)hv8;
    }
  }
  block_stats_atomic<8>(s, q, st1);
}

// xr1 = relu(bn1(y1)) stats; grid-strided NHWC streaming, grid 1024.
__global__ __launch_bounds__(256) void k_xr1_stats(
    const f16* __restrict__ y1, const float* __restrict__ g1,
    const float* __restrict__ b1, const double* __restrict__ st1,
    double* __restrict__ st2) {
  float a1[8], c1[8];
#pragma unroll
  for (int c = 0; c < 8; ++c) {
    double sd = STG(st1, 2 * c), qd = STG(st1, 2 * c + 1);
    double md = sd / CNT1;
    float inv = (float)(1.0 / sqrt(qd / CNT1 - md * md + (double)EPS_BN));
    a1[c] = inv * g1[c];
    c1[c] = b1[c] - (float)md * a1[c];
  }
  const size_t base = (size_t)blockIdx.x * 4096 + threadIdx.x;
  float s[8], q[8];
#pragma unroll
  for (int c = 0; c < 8; ++c) { s[c] = 0.f; q[c] = 0.f; }
#pragma unroll
  for (int k = 0; k < 16; ++k) {
    f16x8 v = *(const f16x8*)&y1[(base + (size_t)k * 256) * 8];
#pragma unroll
    for (int c = 0; c < 8; ++c) {
      float xr = fmaxf((float)v[c] * a1[c] + c1[c], 0.f);
      s[c] += xr; q[c] += xr * xr;
    }
  }
  block_stats_atomic<8>(s, q, st2);
}

// y1 NHWC -> BN1+relu -> scale-expand -> BN2+relu -> 2x2 maxpool
// -> h1 bf16 NHWC [img][256px][16c]. 4 images per block, grid 1024.
__global__ __launch_bounds__(256) void k_l1_out(
    const f16* __restrict__ y1, const float* __restrict__ g1,
    const float* __restrict__ b1, const float* __restrict__ dsew,
    const float* __restrict__ bng, const float* __restrict__ bnb,
    const double* __restrict__ st1, const double* __restrict__ st2,
    short* __restrict__ h1) {
  __shared__ float cA1[8], cC1[8], cS2[16], cO2[16];
  const int tid = threadIdx.x;
  if (tid < 16) {
    const int i = tid >> 1, g = tid & 1;
    double sd = STG(st1, 2 * i), qd = STG(st1, 2 * i + 1);
    double md = sd / CNT1;
    float inv1 = (float)(1.0 / sqrt(qd / CNT1 - md * md + (double)EPS_BN));
    float a1 = inv1 * g1[i];
    if (g == 0) { cA1[i] = a1; cC1[i] = b1[i] - (float)md * a1; }
    double s2 = STG(st2, 2 * i), q2 = STG(st2, 2 * i + 1);
    double mx = s2 / CNT1, vx = q2 / CNT1 - mx * mx;
    float w = dsew[i * 2 + g];
    double inv2 = 1.0 / sqrt((double)w * w * vx + (double)EPS_BN);
    cS2[tid] = (float)(w * inv2) * bng[tid];
    cO2[tid] = bnb[tid] - (float)(w * mx * inv2) * bng[tid];
  }
  __syncthreads();
  const int sub = tid >> 6, lane = tid & 63;
  const int n = blockIdx.x * 4 + sub;
#pragma unroll
  for (int w = 0; w < 4; ++w) {
    const int opx = w * 64 + lane, oy = opx >> 4, ox = opx & 15;
    const size_t pbase = ((size_t)n * 1024 + (size_t)(2 * oy) * 32 + 2 * ox) * 8;
    f16x8 vA = *(const f16x8*)&y1[pbase];
    f16x8 vB = *(const f16x8*)&y1[pbase + 8];
    f16x8 vC = *(const f16x8*)&y1[pbase + 256];
    f16x8 vD = *(const f16x8*)&y1[pbase + 264];
    short hv[16];
#pragma unroll
    for (int i = 0; i < 8; ++i) {
      float a1 = cA1[i], c1 = cC1[i];
      float xr0 = fmaxf((float)vA[i] * a1 + c1, 0.f);
      float xr1 = fmaxf((float)vB[i] * a1 + c1, 0.f);
      float xr2 = fmaxf((float)vC[i] * a1 + c1, 0.f);
      float xr3 = fmaxf((float)vD[i] * a1 + c1, 0.f);
#pragma unroll
      for (int g = 0; g < 2; ++g) {
        const int c = 2 * i + g;
        float sc = cS2[c], of = cO2[c];
        float r0 = fmaxf(xr0 * sc + of, 0.f);
        float r1 = fmaxf(xr1 * sc + of, 0.f);
        float r2 = fmaxf(xr2 * sc + of, 0.f);
        float r3 = fmaxf(xr3 * sc + of, 0.f);
        hv[c] = f2bf(fmaxf(fmaxf(r0, r1), fmaxf(r2, r3)));
      }
    }
    uint4* dst = (uint4*)&h1[((size_t)n * 256 + opx) * 16];
    dst[0] = ((uint4*)hv)[0];
    dst[1] = ((uint4*)hv)[1];
  }
}

// ---------------- layer 2 conv via MFMA (R7 form: grid 512, 8 img) ----------
__global__ __launch_bounds__(256) void k_conv2_mfma(
    const short* __restrict__ h1, const float* __restrict__ w2,
    float* __restrict__ y2, double* __restrict__ st3) {
  __shared__ short smem[4 * 5184 + 10 * 256];
  __shared__ float red[4][32];
  short* hs = smem;
  short* wt = smem + 4 * 5184;
  const int tid = threadIdx.x, wid = tid >> 6, lane = tid & 63;
  for (int i = tid; i < (4 * 5184 + 10 * 256) / 2; i += 256) ((int*)smem)[i] = 0;
  __syncthreads();
  for (int i = tid; i < 2304; i += 256) {
    const int s = i >> 8, co = (i >> 4) & 15, ci = i & 15;
    wt[i] = f2bf(w2[(co * 16 + ci) * 9 + s]);
  }
  const int c = lane & 15, quad = lane >> 4;
  const int ci0 = (quad & 1) * 8;
  int aoff[5];
#pragma unroll
  for (int p = 0; p < 5; ++p) {
    int s = 2 * p + (quad >> 1);
    if (s > 8) s = 8;  // address clamp; B-frag for that k-half is zero
    const int dy = s / 3, dx = s % 3;
    aoff[p] = (dy * 18 + (c + dx)) * 16 + ci0;
  }
  float ssum = 0.f, qsum = 0.f;
  for (int it = 0; it < 2; ++it) {
    __syncthreads();
    {  // stage 4 images (interior only; borders stay zero)
      const uint4* src =
          (const uint4*)(h1 + ((size_t)blockIdx.x * 8 + it * 4) * 4096);
      for (int ch = tid; ch < 2048; ch += 256) {
        const int im = ch >> 9, j = ch & 511, px = j >> 1, half = j & 1;
        const int r = px >> 4, cc2 = px & 15;
        *(uint4*)&hs[im * 5184 + ((r + 1) * 18 + (cc2 + 1)) * 16 + half * 8] =
            src[ch];
      }
    }
    __syncthreads();
    bf16x8 bf[5];
#pragma unroll
    for (int p = 0; p < 5; ++p) {
      const int s = 2 * p + (quad >> 1);  // s==9 -> wt slot 9 == zeros
      bf[p] = *(const bf16x8*)&wt[s * 256 + c * 16 + ci0];
    }
    const short* hbase = hs + wid * 5184;
    const int img = blockIdx.x * 8 + it * 4 + wid;
    float* yp = y2 + ((size_t)img * 16 + c) * 256 + quad * 4;
    for (int r = 0; r < 16; ++r) {
      f32x4 acc = {0.f, 0.f, 0.f, 0.f};
#pragma unroll
      for (int p = 0; p < 5; ++p) {
        bf16x8 a = *(const bf16x8*)&hbase[r * 288 + aoff[p]];
        acc = __builtin_amdgcn_mfma_f32_16x16x32_bf16(a, bf[p], acc, 0, 0, 0);
      }
      *(float4*)&yp[r * 16] = *(float4*)&acc;
#pragma unroll
      for (int g = 0; g < 4; ++g) { float v = acc[g]; ssum += v; qsum += v * v; }
    }
  }
  ssum += __shfl_down(ssum, 32, 64); ssum += __shfl_down(ssum, 16, 64);
  qsum += __shfl_down(qsum, 32, 64); qsum += __shfl_down(qsum, 16, 64);
  if (lane < 16) { red[wid][lane] = ssum; red[wid][16 + lane] = qsum; }
  __syncthreads();
  if (tid < 32) {
    const int cc2 = tid & 15, isq = tid >> 4;
    float v = red[0][isq * 16 + cc2] + red[1][isq * 16 + cc2] +
              red[2][isq * 16 + cc2] + red[3][isq * 16 + cc2];
    unsafeAtomicAdd(st3 + (size_t)(2 * cc2 + isq) * 8, (double)v);
  }
}

__global__ __launch_bounds__(256) void k_xr2_stats(
    const float* __restrict__ y2, const float* __restrict__ g2,
    const float* __restrict__ b2, const double* __restrict__ st3,
    double* __restrict__ st4) {
  const int c = blockIdx.x & 15, n0 = (blockIdx.x >> 4) << 4;
  double sd = STG(st3, 2 * c), qd = STG(st3, 2 * c + 1);
  double md = sd / CNT2;
  float m = (float)md;
  float inv = (float)(1.0 / sqrt(qd / CNT2 - md * md + (double)EPS_BN));
  float gg = g2[c], bb = b2[c];
  float s = 0.f, q = 0.f;
#pragma unroll
  for (int k = 0; k < 16; ++k) {
    float v = y2[((size_t)(n0 + k) * 16 + c) * 256 + threadIdx.x];
    float xr = fmaxf((v - m) * inv * gg + bb, 0.f);
    s += xr; q += xr * xr;
  }
  block_stats_atomic<1>(&s, &q, st4 + (size_t)(2 * c) * 8);
}

// y2 -> BN+relu -> scale-expand -> BN+relu -> 2x2 maxpool -> h2 bf16 [4096,2048]
__global__ __launch_bounds__(256) void k_l2_out(
    const float* __restrict__ y2, const float* __restrict__ g2,
    const float* __restrict__ b2, const float* __restrict__ dsew,
    const float* __restrict__ bng, const float* __restrict__ bnb,
    const double* __restrict__ st3, const double* __restrict__ st4,
    short* __restrict__ h2) {
  __shared__ float cS3[16], cO3[16], cS4[32], cO4[32];
  const int tid = threadIdx.x;
  if (tid < 32) {
    const int i = tid >> 1, g = tid & 1;
    double sd = STG(st3, 2 * i), qd = STG(st3, 2 * i + 1);
    double md = sd / CNT2;
    float inv3 = (float)(1.0 / sqrt(qd / CNT2 - md * md + (double)EPS_BN));
    float a3 = inv3 * g2[i];
    if (g == 0) { cS3[i] = a3; cO3[i] = b2[i] - (float)md * a3; }
    double s4 = STG(st4, 2 * i), q4 = STG(st4, 2 * i + 1);
    double mx = s4 / CNT2, vx = q4 / CNT2 - mx * mx;
    float w = dsew[2 * i + g];
    double inv4 = 1.0 / sqrt((double)w * w * vx + (double)EPS_BN);
    cS4[tid] = (float)(w * inv4) * bng[tid];
    cO4[tid] = bnb[tid] - (float)(w * mx * inv4) * bng[tid];
  }
  __syncthreads();
  const int sub = tid >> 6, lane = tid & 63;
  const int n = blockIdx.x * 4 + sub;
  const int px = lane & 7, py = lane >> 3;
#pragma unroll
  for (int i = 0; i < 16; ++i) {
    const size_t base = ((size_t)n * 16 + i) * 256;
    float2 v01 = *(const float2*)&y2[base + (2 * py) * 16 + 2 * px];
    float2 v23 = *(const float2*)&y2[base + (2 * py + 1) * 16 + 2 * px];
    float a3 = cS3[i], c3 = cO3[i];
    float xr0 = fmaxf(v01.x * a3 + c3, 0.f);
    float xr1 = fmaxf(v01.y * a3 + c3, 0.f);
    float xr2 = fmaxf(v23.x * a3 + c3, 0.f);
    float xr3 = fmaxf(v23.y * a3 + c3, 0.f);
#pragma unroll
    for (int g = 0; g < 2; ++g) {
      const int c = 2 * i + g;
      float sc = cS4[c], of = cO4[c];
      float r0 = fmaxf(xr0 * sc + of, 0.f);
      float r1 = fmaxf(xr1 * sc + of, 0.f);
      float r2 = fmaxf(xr2 * sc + of, 0.f);
      float r3 = fmaxf(xr3 * sc + of, 0.f);
      h2[(size_t)n * 2048 + c * 64 + py * 8 + px] =
          f2bf(fmaxf(fmaxf(r0, r1), fmaxf(r2, r3)));
    }
  }
}

// cast fc1_w/fc2_w to bf16 (vectorized) + zero stat slots
__global__ __launch_bounds__(256) void k_cast_w(const float* __restrict__ w1,
                                                const float* __restrict__ w2,
                                                short* __restrict__ o1,
                                                short* __restrict__ o2,
                                                double* __restrict__ st) {
  const int i4 = blockIdx.x * 256 + threadIdx.x;
  if (blockIdx.x == 0) {
    for (int k = threadIdx.x; k < 768; k += 256) st[k] = 0.0;
  }
  if (i4 < 262144) {
    float4 v = ((const float4*)w1)[i4];
    short h[4] = {f2bf(v.x), f2bf(v.y), f2bf(v.z), f2bf(v.w)};
    ((uint2*)o1)[i4] = *(uint2*)h;
  } else if (i4 < 327680) {
    const int j = i4 - 262144;
    float4 v = ((const float4*)w2)[j];
    short h[4] = {f2bf(v.x), f2bf(v.y), f2bf(v.z), f2bf(v.w)};
    ((uint2*)o2)[j] = *(uint2*)h;
  }
}

// ------------- FC via MFMA: C[M,512] = act(A[M,K]bf16 @ W[512,K]bf16^T + b) --
template <int K, int RELU, int OUT_BF16>
__global__ __launch_bounds__(256) void k_fc_mfma(
    const short* __restrict__ A, const short* __restrict__ W,
    const float* __restrict__ bias, void* __restrict__ Cv) {
  const int wv = threadIdx.x >> 6, lane = threadIdx.x & 63;
  const int bm = blockIdx.y * 64;
  const int bn = blockIdx.x * 64 + wv * 16;
  const int cl = lane & 15, quad = lane >> 4;
  const short* ap = A + (size_t)(bm + cl) * K + quad * 8;
  const short* bp = W + (size_t)(bn + cl) * K + quad * 8;
  f32x4 acc0 = {0.f, 0.f, 0.f, 0.f}, acc1 = acc0, acc2 = acc0, acc3 = acc0;
#pragma unroll 4
  for (int k0 = 0; k0 < K; k0 += 32) {
    bf16x8 b = *(const bf16x8*)bp;
    bf16x8 a0 = *(const bf16x8*)ap;
    bf16x8 a1 = *(const bf16x8*)(ap + (size_t)16 * K);
    bf16x8 a2 = *(const bf16x8*)(ap + (size_t)32 * K);
    bf16x8 a3 = *(const bf16x8*)(ap + (size_t)48 * K);
    ap += 32; bp += 32;
    acc0 = __builtin_amdgcn_mfma_f32_16x16x32_bf16(a0, b, acc0, 0, 0, 0);
    acc1 = __builtin_amdgcn_mfma_f32_16x16x32_bf16(a1, b, acc1, 0, 0, 0);
    acc2 = __builtin_amdgcn_mfma_f32_16x16x32_bf16(a2, b, acc2, 0, 0, 0);
    acc3 = __builtin_amdgcn_mfma_f32_16x16x32_bf16(a3, b, acc3, 0, 0, 0);
  }
  const float bia = bias[bn + cl];
  f32x4 av[4] = {acc0, acc1, acc2, acc3};
#pragma unroll
  for (int rt = 0; rt < 4; ++rt) {
#pragma unroll
    for (int r = 0; r < 4; ++r) {
      const int row = bm + rt * 16 + quad * 4 + r;
      float v = av[rt][r] + bia;
      if (RELU) v = fmaxf(v, 0.f);
      if (OUT_BF16)
        ((short*)Cv)[(size_t)row * 512 + bn + cl] = f2bf(v);
      else
        ((float*)Cv)[(size_t)row * 512 + bn + cl] = v;
    }
  }
}

// fc3: one wave per row, N=10, K=512, fp32
__global__ __launch_bounds__(256) void k_fc3(const float* __restrict__ A,
                                             const float* __restrict__ W,
                                             const float* __restrict__ b,
                                             float* __restrict__ out) {
  const int wid = threadIdx.x >> 6, lane = threadIdx.x & 63;
  const int row = blockIdx.x * 4 + wid;
  float p[10];
#pragma unroll
  for (int o = 0; o < 10; ++o) p[o] = 0.f;
  const float* a = A + (size_t)row * 512;
#pragma unroll
  for (int jj = 0; jj < 8; ++jj) {
    const int j = lane + jj * 64;
    float av = a[j];
#pragma unroll
    for (int o = 0; o < 10; ++o) p[o] += av * W[o * 512 + j];
  }
#pragma unroll
  for (int o = 0; o < 10; ++o) p[o] = wave_sum(p[o]);
  if (lane == 0) {
#pragma unroll
    for (int o = 0; o < 10; ++o) out[(size_t)row * 10 + o] = p[o] + b[o];
  }
}

}  // namespace

extern "C" void kernel_launch(void* const* d_in, const int* in_sizes, int n_in,
                              void* d_out, int out_size, void* d_ws,
                              size_t ws_size, hipStream_t stream) {
  const float* x      = (const float*)d_in[0];
  const float* dfe1_w = (const float*)d_in[1];
  const float* dse1_g = (const float*)d_in[2];
  const float* dse1_b = (const float*)d_in[3];
  const float* dse1_w = (const float*)d_in[4];
  const float* bn1_g  = (const float*)d_in[5];
  const float* bn1_b  = (const float*)d_in[6];
  const float* dfe2_w = (const float*)d_in[7];
  const float* dse2_g = (const float*)d_in[8];
  const float* dse2_b = (const float*)d_in[9];
  const float* dse2_w = (const float*)d_in[10];
  const float* bn2_g  = (const float*)d_in[11];
  const float* bn2_b  = (const float*)d_in[12];
  const float* fc1_w  = (const float*)d_in[13];
  const float* fc1_b  = (const float*)d_in[14];
  const float* fc2_w  = (const float*)d_in[15];
  const float* fc2_b  = (const float*)d_in[16];
  const float* fc3_w  = (const float*)d_in[17];
  const float* fc3_b  = (const float*)d_in[18];
  float* out = (float*)d_out;
  char* ws = (char*)d_ws;
  short* h1 = (short*)(ws + OFF_H1);
  f16* y1 = (f16*)(ws + OFF_Y1);
  float* y2 = (float*)(ws + OFF_Y2);
  short* h2 = (short*)(ws + OFF_H2);
  short* a1 = (short*)(ws + OFF_A1);
  float* a2 = (float*)(ws + OFF_A2);
  short* wb1 = (short*)(ws + OFF_WB1);
  short* wb2 = (short*)(ws + OFF_WB2);
  double* st = (double*)(ws + OFF_ST);
  double* ST1 = st;
  double* ST2 = st + (size_t)16 * 8;
  double* ST3 = st + (size_t)32 * 8;
  double* ST4 = st + (size_t)64 * 8;

  k_cast_w<<<1280, 256, 0, stream>>>(fc1_w, fc2_w, wb1, wb2, st);
  k_conv1_y1<<<1024, 256, 0, stream>>>(x, dfe1_w, y1, ST1);
  k_xr1_stats<<<1024, 256, 0, stream>>>(y1, dse1_g, dse1_b, ST1, ST2);
  k_l1_out<<<1024, 256, 0, stream>>>(y1, dse1_g, dse1_b, dse1_w, bn1_g, bn1_b,
                                     ST1, ST2, h1);
  k_conv2_mfma<<<512, 256, 0, stream>>>(h1, dfe2_w, y2, ST3);
  k_xr2_stats<<<4096, 256, 0, stream>>>(y2, dse2_g, dse2_b, ST3, ST4);
  k_l2_out<<<1024, 256, 0, stream>>>(y2, dse2_g, dse2_b, dse2_w, bn2_g, bn2_b,
                                     ST3, ST4, h2);
  k_fc_mfma<2048, 1, 1><<<dim3(8, 64), 256, 0, stream>>>(h2, wb1, fc1_b, a1);
  k_fc_mfma<512, 1, 0><<<dim3(8, 64), 256, 0, stream>>>(a1, wb2, fc2_b, a2);
  k_fc3<<<1024, 256, 0, stream>>>(a2, fc3_w, fc3_b, out);
}

// Round 12
// 378.397 us; speedup vs baseline: 4.3730x; 1.0426x over previous
//
#include <hip/hip_runtime.h>
#include <math.h>

#define EPS_BN 1e-5

namespace {

constexpr double CNT1 = 4096.0 * 1024.0;  // layer1 BN count: B*32*32
constexpr double CNT2 = 4096.0 * 256.0;   // layer2 BN count: B*16*16

// workspace layout (bytes). Required ws >= ~131 MiB.
constexpr size_t OFF_Y1 = 0;            // [4096,1024px,8ch] f16 = 64 MiB (live thru conv2)
constexpr size_t OFF_Y2 = 67108864;     // [4096,16ch,256px] f16 = 32 MiB
constexpr size_t OFF_H2 = 100663296;    // [4096,2048] bf16 = 16 MiB
constexpr size_t OFF_A1 = 117440512;    // [4096,512] bf16 = 4 MiB
constexpr size_t OFF_A2 = 121634816;    // [4096,512] f32 = 8 MiB
constexpr size_t OFF_ST = 134217728;    // BN stats: 96 slots x 64B
constexpr size_t OFF_WB1 = 134283264;   // fc1_w bf16 [512,2048] = 2 MiB
constexpr size_t OFF_WB2 = 136380416;   // fc2_w bf16 [512,512] = 0.5 MiB

#define STG(p, i) (p)[(size_t)(i) * 8]

typedef short bf16x8 __attribute__((ext_vector_type(8)));
typedef float f32x4 __attribute__((ext_vector_type(4)));
typedef _Float16 f16;
typedef _Float16 f16x2 __attribute__((ext_vector_type(2)));
typedef _Float16 f16x4 __attribute__((ext_vector_type(4)));
typedef _Float16 f16x8 __attribute__((ext_vector_type(8)));

__device__ __forceinline__ short f2bf(float f) {
  unsigned u = __float_as_uint(f);
  u = (u + 0x7fffu + ((u >> 16) & 1u)) >> 16;
  return (short)u;
}

__device__ __forceinline__ float wave_sum(float v) {
#pragma unroll
  for (int o = 32; o > 0; o >>= 1) v += __shfl_down(v, o, 64);
  return v;
}

template <int NV>
__device__ __forceinline__ void block_stats_atomic(const float* s, const float* q,
                                                   double* __restrict__ st) {
  __shared__ float red[4][NV * 2];
  const int lane = threadIdx.x & 63, wid = threadIdx.x >> 6;
#pragma unroll
  for (int c = 0; c < NV; ++c) {
    float sv = wave_sum(s[c]);
    float qv = wave_sum(q[c]);
    if (lane == 0) { red[wid][2 * c] = sv; red[wid][2 * c + 1] = qv; }
  }
  __syncthreads();
  if (threadIdx.x < NV * 2) {
    float v = red[0][threadIdx.x] + red[1][threadIdx.x] + red[2][threadIdx.x] +
              red[3][threadIdx.x];
    unsafeAtomicAdd(st + (size_t)threadIdx.x * 8, (double)v);
  }
}

// ---------------- layer 1: conv 3x3, 3->8, on 32x32, pad 1 -------------------
// R11 form (best measured, 87 us): thread = 4 consecutive px in row rr,
// double-buffered x staging, 4 images/block, grid 1024.
// Writes y1 f16 NHWC [n][1024px][8ch] + raw-y1 stats.
__global__ __launch_bounds__(256) void k_conv1_y1(
    const float* __restrict__ x, const float* __restrict__ w1,
    f16* __restrict__ y1, double* __restrict__ st1) {
  __shared__ __align__(16) float xs[2][3 * 1224];  // 2 x (3 x 34 x 36)
  __shared__ __align__(16) float wk[216];
  const int tid = threadIdx.x;
  for (int i = tid; i < 2 * 3 * 1224; i += 256) (&xs[0][0])[i] = 0.f;
  if (tid < 216) wk[(tid % 27) * 8 + tid / 27] = w1[tid];
  const int rr = tid >> 3, c0 = (tid & 7) * 4;
  const int n0 = blockIdx.x * 4;
  float s[8], q[8];
#pragma unroll
  for (int c = 0; c < 8; ++c) { s[c] = 0.f; q[c] = 0.f; }
  __syncthreads();  // zero-init + wk visible
  {  // prologue: stage image 0 into buf 0
    const float* xp = x + (size_t)n0 * 3072;
    for (int i = tid; i < 3072; i += 256) {
      int ci = i >> 10, r = (i >> 5) & 31, c = i & 31;
      xs[0][ci * 1224 + (r + 1) * 36 + (c + 1)] = xp[i];
    }
  }
#pragma unroll 1
  for (int img = 0; img < 4; ++img) {
    const int buf = img & 1;
    __syncthreads();  // buf staged; previous compute on buf^1 finished
    if (img + 1 < 4) {  // stage next image into the other buffer (overlaps)
      const float* xp = x + (size_t)(n0 + img + 1) * 3072;
      for (int i = tid; i < 3072; i += 256) {
        int ci = i >> 10, r = (i >> 5) & 31, c = i & 31;
        xs[buf ^ 1][ci * 1224 + (r + 1) * 36 + (c + 1)] = xp[i];
      }
    }
    float acc[4][8];
#pragma unroll
    for (int p = 0; p < 4; ++p)
#pragma unroll
      for (int co = 0; co < 8; ++co) acc[p][co] = 0.f;
#pragma unroll
    for (int ci = 0; ci < 3; ++ci)
#pragma unroll
      for (int dy = 0; dy < 3; ++dy) {
        const float* rowp = &xs[buf][ci * 1224 + (rr + dy) * 36 + c0];
        float xw[6];
        *(float4*)&xw[0] = *(const float4*)rowp;
        *(float2*)&xw[4] = *(const float2*)(rowp + 4);
#pragma unroll
        for (int dx = 0; dx < 3; ++dx) {
          const int j = ci * 9 + dy * 3 + dx;
          float wv[8];
          *(float4*)&wv[0] = *(const float4*)&wk[j * 8];
          *(float4*)&wv[4] = *(const float4*)&wk[j * 8 + 4];
#pragma unroll
          for (int p = 0; p < 4; ++p)
#pragma unroll
            for (int co = 0; co < 8; ++co) acc[p][co] += xw[p + dx] * wv[co];
        }
      }
    f16* yp = &y1[((size_t)(n0 + img) * 1024 + rr * 32 + c0) * 8];
#pragma unroll
    for (int p = 0; p < 4; ++p) {
      f16 hv8[8];
#pragma unroll
      for (int co = 0; co < 8; ++co) {
        float v = acc[p][co];
        s[co] += v; q[co] += v * v;
        hv8[co] = (f16)v;
      }
      *(uint4*)&yp[p * 8] = *(uint4*)hv8;
    }
  }
  block_stats_atomic<8>(s, q, st1);
}

// xr1 = relu(bn1(y1)) stats; grid-strided NHWC streaming, grid 1024.
__global__ __launch_bounds__(256) void k_xr1_stats(
    const f16* __restrict__ y1, const float* __restrict__ g1,
    const float* __restrict__ b1, const double* __restrict__ st1,
    double* __restrict__ st2) {
  float a1[8], c1[8];
#pragma unroll
  for (int c = 0; c < 8; ++c) {
    double sd = STG(st1, 2 * c), qd = STG(st1, 2 * c + 1);
    double md = sd / CNT1;
    float inv = (float)(1.0 / sqrt(qd / CNT1 - md * md + (double)EPS_BN));
    a1[c] = inv * g1[c];
    c1[c] = b1[c] - (float)md * a1[c];
  }
  const size_t base = (size_t)blockIdx.x * 4096 + threadIdx.x;
  float s[8], q[8];
#pragma unroll
  for (int c = 0; c < 8; ++c) { s[c] = 0.f; q[c] = 0.f; }
#pragma unroll
  for (int k = 0; k < 16; ++k) {
    f16x8 v = *(const f16x8*)&y1[(base + (size_t)k * 256) * 8];
#pragma unroll
    for (int c = 0; c < 8; ++c) {
      float xr = fmaxf((float)v[c] * a1[c] + c1[c], 0.f);
      s[c] += xr; q[c] += xr * xr;
    }
  }
  block_stats_atomic<8>(s, q, st2);
}

// ---------- FUSED: l1 epilogue + layer-2 conv via MFMA -----------------------
// Staging computes h1 values ON THE FLY from y1 (BN1+relu+scale+BN2+relu+pool)
// directly into conv2's padded LDS tile — h1 never touches HBM.
// R7 shape otherwise: 8 images/block (2 iters of 4), grid 512.
// Writes y2 f16 channel-major [img][16co][256px] + stats (on rounded values).
__global__ __launch_bounds__(256) void k_conv2_fused(
    const f16* __restrict__ y1, const float* __restrict__ g1,
    const float* __restrict__ b1, const float* __restrict__ dsew,
    const float* __restrict__ bng, const float* __restrict__ bnb,
    const float* __restrict__ w2, const double* __restrict__ st1,
    const double* __restrict__ st2, f16* __restrict__ y2,
    double* __restrict__ st3) {
  __shared__ short smem[4 * 5184 + 10 * 256];
  __shared__ float red[4][32];
  __shared__ float cA1[8], cC1[8], cS2[16], cO2[16];
  short* hs = smem;                 // 4 padded images [18][18][16ch]
  short* wt = smem + 4 * 5184;      // [10][16co][16ci], slot 9 stays zero
  const int tid = threadIdx.x, wid = tid >> 6, lane = tid & 63;
  for (int i = tid; i < (4 * 5184 + 10 * 256) / 2; i += 256) ((int*)smem)[i] = 0;
  if (tid < 16) {  // l1 epilogue coefficients (identical math to old l1_out)
    const int i = tid >> 1, g = tid & 1;
    double sd = STG(st1, 2 * i), qd = STG(st1, 2 * i + 1);
    double md = sd / CNT1;
    float inv1 = (float)(1.0 / sqrt(qd / CNT1 - md * md + (double)EPS_BN));
    float a1 = inv1 * g1[i];
    if (g == 0) { cA1[i] = a1; cC1[i] = b1[i] - (float)md * a1; }
    double s2 = STG(st2, 2 * i), q2 = STG(st2, 2 * i + 1);
    double mx = s2 / CNT1, vx = q2 / CNT1 - mx * mx;
    float w = dsew[i * 2 + g];
    double inv2 = 1.0 / sqrt((double)w * w * vx + (double)EPS_BN);
    cS2[tid] = (float)(w * inv2) * bng[tid];
    cO2[tid] = bnb[tid] - (float)(w * mx * inv2) * bng[tid];
  }
  __syncthreads();
  for (int i = tid; i < 2304; i += 256) {
    const int s = i >> 8, co = (i >> 4) & 15, ci = i & 15;
    wt[i] = f2bf(w2[(co * 16 + ci) * 9 + s]);
  }
  const int c = lane & 15, quad = lane >> 4;
  const int ci0 = (quad & 1) * 8;
  int aoff[5];
#pragma unroll
  for (int p = 0; p < 5; ++p) {
    int s = 2 * p + (quad >> 1);
    if (s > 8) s = 8;  // address clamp; B-frag for that k-half is zero
    const int dy = s / 3, dx = s % 3;
    aoff[p] = (dy * 18 + (c + dx)) * 16 + ci0;
  }
  float ssum = 0.f, qsum = 0.f;
  for (int it = 0; it < 2; ++it) {
    const int n0 = blockIdx.x * 8 + it * 4;
    __syncthreads();
    // stage 4 images: compute h1 from y1 + epilogue, write padded LDS tile.
    // element e = (im, px, half): half selects output channels 0-7 / 8-15.
    for (int e = tid; e < 2048; e += 256) {
      const int im = e >> 9, j = e & 511, px = j >> 1, half = j & 1;
      const int r = px >> 4, cx = px & 15;
      const size_t pb =
          ((size_t)(n0 + im) * 1024 + (size_t)(2 * r) * 32 + 2 * cx) * 8 +
          half * 4;
      f16x4 vA = *(const f16x4*)&y1[pb];        // (2r,   2cx)
      f16x4 vB = *(const f16x4*)&y1[pb + 8];    // (2r,   2cx+1)
      f16x4 vC = *(const f16x4*)&y1[pb + 256];  // (2r+1, 2cx)
      f16x4 vD = *(const f16x4*)&y1[pb + 264];  // (2r+1, 2cx+1)
      short hv[8];
#pragma unroll
      for (int ii = 0; ii < 4; ++ii) {
        const int i = half * 4 + ii;
        float a = cA1[i], cb = cC1[i];
        float x0 = fmaxf((float)vA[ii] * a + cb, 0.f);
        float x1 = fmaxf((float)vB[ii] * a + cb, 0.f);
        float x2 = fmaxf((float)vC[ii] * a + cb, 0.f);
        float x3 = fmaxf((float)vD[ii] * a + cb, 0.f);
#pragma unroll
        for (int g = 0; g < 2; ++g) {
          const int ch = 2 * i + g;
          float sc = cS2[ch], of = cO2[ch];
          float r0 = fmaxf(x0 * sc + of, 0.f);
          float r1 = fmaxf(x1 * sc + of, 0.f);
          float r2 = fmaxf(x2 * sc + of, 0.f);
          float r3 = fmaxf(x3 * sc + of, 0.f);
          hv[ii * 2 + g] = f2bf(fmaxf(fmaxf(r0, r1), fmaxf(r2, r3)));
        }
      }
      *(uint4*)&hs[im * 5184 + ((r + 1) * 18 + (cx + 1)) * 16 + half * 8] =
          *(uint4*)hv;
    }
    __syncthreads();
    bf16x8 bf[5];
#pragma unroll
    for (int p = 0; p < 5; ++p) {
      const int s = 2 * p + (quad >> 1);  // s==9 -> wt slot 9 == zeros
      bf[p] = *(const bf16x8*)&wt[s * 256 + c * 16 + ci0];
    }
    const short* hbase = hs + wid * 5184;
    const int img = n0 + wid;
    f16* yp = y2 + ((size_t)img * 16 + c) * 256 + quad * 4;
    for (int r = 0; r < 16; ++r) {
      f32x4 acc = {0.f, 0.f, 0.f, 0.f};
#pragma unroll
      for (int p = 0; p < 5; ++p) {
        bf16x8 a = *(const bf16x8*)&hbase[r * 288 + aoff[p]];
        acc = __builtin_amdgcn_mfma_f32_16x16x32_bf16(a, bf[p], acc, 0, 0, 0);
      }
      f16 hv[4];
#pragma unroll
      for (int g = 0; g < 4; ++g) {
        hv[g] = (f16)acc[g];
        float v = (float)hv[g];  // stats on rounded value (self-consistent)
        ssum += v; qsum += v * v;
      }
      *(f16x4*)&yp[r * 16] = *(f16x4*)hv;
    }
  }
  // lanes {l, l+16, l+32, l+48} share co = l&15
  ssum += __shfl_down(ssum, 32, 64); ssum += __shfl_down(ssum, 16, 64);
  qsum += __shfl_down(qsum, 32, 64); qsum += __shfl_down(qsum, 16, 64);
  if (lane < 16) { red[wid][lane] = ssum; red[wid][16 + lane] = qsum; }
  __syncthreads();
  if (tid < 32) {
    const int cc2 = tid & 15, isq = tid >> 4;
    float v = red[0][isq * 16 + cc2] + red[1][isq * 16 + cc2] +
              red[2][isq * 16 + cc2] + red[3][isq * 16 + cc2];
    unsafeAtomicAdd(st3 + (size_t)(2 * cc2 + isq) * 8, (double)v);
  }
}

// xr2 = relu(bn3(y2)) stats; 8 images/block, 16B vector reads, grid 512.
__global__ __launch_bounds__(256) void k_xr2_stats(
    const f16* __restrict__ y2, const float* __restrict__ g2,
    const float* __restrict__ b2, const double* __restrict__ st3,
    double* __restrict__ st4) {
  __shared__ float red[32];
  const int tid = threadIdx.x, c = tid >> 4, seg = tid & 15;
  double sd = STG(st3, 2 * c), qd = STG(st3, 2 * c + 1);
  double md = sd / CNT2;
  float inv = (float)(1.0 / sqrt(qd / CNT2 - md * md + (double)EPS_BN));
  float a3 = inv * g2[c];
  float c3 = b2[c] - (float)md * a3;
  float s = 0.f, q = 0.f;
#pragma unroll
  for (int k = 0; k < 8; ++k) {
    const f16* p =
        &y2[(((size_t)(blockIdx.x * 8 + k)) * 16 + c) * 256 + seg * 16];
    f16x8 v0 = *(const f16x8*)p;
    f16x8 v1 = *(const f16x8*)(p + 8);
#pragma unroll
    for (int j = 0; j < 8; ++j) {
      float x0 = fmaxf((float)v0[j] * a3 + c3, 0.f);
      float x1 = fmaxf((float)v1[j] * a3 + c3, 0.f);
      s += x0 + x1; q += x0 * x0 + x1 * x1;
    }
  }
#pragma unroll
  for (int o = 8; o > 0; o >>= 1) {
    s += __shfl_down(s, o, 64);
    q += __shfl_down(q, o, 64);
  }
  if ((tid & 15) == 0) { red[2 * c] = s; red[2 * c + 1] = q; }
  __syncthreads();
  if (tid < 32) unsafeAtomicAdd(st4 + (size_t)tid * 8, (double)red[tid]);
}

// y2 f16 -> BN+relu -> scale-expand -> BN+relu -> 2x2 maxpool -> h2 bf16
__global__ __launch_bounds__(256) void k_l2_out(
    const f16* __restrict__ y2, const float* __restrict__ g2,
    const float* __restrict__ b2, const float* __restrict__ dsew,
    const float* __restrict__ bng, const float* __restrict__ bnb,
    const double* __restrict__ st3, const double* __restrict__ st4,
    short* __restrict__ h2) {
  __shared__ float cS3[16], cO3[16], cS4[32], cO4[32];
  const int tid = threadIdx.x;
  if (tid < 32) {
    const int i = tid >> 1, g = tid & 1;
    double sd = STG(st3, 2 * i), qd = STG(st3, 2 * i + 1);
    double md = sd / CNT2;
    float inv3 = (float)(1.0 / sqrt(qd / CNT2 - md * md + (double)EPS_BN));
    float a3 = inv3 * g2[i];
    if (g == 0) { cS3[i] = a3; cO3[i] = b2[i] - (float)md * a3; }
    double s4 = STG(st4, 2 * i), q4 = STG(st4, 2 * i + 1);
    double mx = s4 / CNT2, vx = q4 / CNT2 - mx * mx;
    float w = dsew[2 * i + g];
    double inv4 = 1.0 / sqrt((double)w * w * vx + (double)EPS_BN);
    cS4[tid] = (float)(w * inv4) * bng[tid];
    cO4[tid] = bnb[tid] - (float)(w * mx * inv4) * bng[tid];
  }
  __syncthreads();
  const int sub = tid >> 6, lane = tid & 63;
  const int n = blockIdx.x * 4 + sub;
  const int px = lane & 7, py = lane >> 3;
#pragma unroll
  for (int i = 0; i < 16; ++i) {
    const size_t base = ((size_t)n * 16 + i) * 256;
    f16x2 v01 = *(const f16x2*)&y2[base + (2 * py) * 16 + 2 * px];
    f16x2 v23 = *(const f16x2*)&y2[base + (2 * py + 1) * 16 + 2 * px];
    float a3 = cS3[i], c3 = cO3[i];
    float xr0 = fmaxf((float)v01[0] * a3 + c3, 0.f);
    float xr1 = fmaxf((float)v01[1] * a3 + c3, 0.f);
    float xr2 = fmaxf((float)v23[0] * a3 + c3, 0.f);
    float xr3 = fmaxf((float)v23[1] * a3 + c3, 0.f);
#pragma unroll
    for (int g = 0; g < 2; ++g) {
      const int c = 2 * i + g;
      float sc = cS4[c], of = cO4[c];
      float r0 = fmaxf(xr0 * sc + of, 0.f);
      float r1 = fmaxf(xr1 * sc + of, 0.f);
      float r2 = fmaxf(xr2 * sc + of, 0.f);
      float r3 = fmaxf(xr3 * sc + of, 0.f);
      h2[(size_t)n * 2048 + c * 64 + py * 8 + px] =
          f2bf(fmaxf(fmaxf(r0, r1), fmaxf(r2, r3)));
    }
  }
}

// cast fc1_w/fc2_w to bf16 (vectorized) + zero stat slots
__global__ __launch_bounds__(256) void k_cast_w(const float* __restrict__ w1,
                                                const float* __restrict__ w2,
                                                short* __restrict__ o1,
                                                short* __restrict__ o2,
                                                double* __restrict__ st) {
  const int i4 = blockIdx.x * 256 + threadIdx.x;
  if (blockIdx.x == 0) {
    for (int k = threadIdx.x; k < 768; k += 256) st[k] = 0.0;
  }
  if (i4 < 262144) {
    float4 v = ((const float4*)w1)[i4];
    short h[4] = {f2bf(v.x), f2bf(v.y), f2bf(v.z), f2bf(v.w)};
    ((uint2*)o1)[i4] = *(uint2*)h;
  } else if (i4 < 327680) {
    const int j = i4 - 262144;
    float4 v = ((const float4*)w2)[j];
    short h[4] = {f2bf(v.x), f2bf(v.y), f2bf(v.z), f2bf(v.w)};
    ((uint2*)o2)[j] = *(uint2*)h;
  }
}

// ------------- FC via MFMA: C[M,512] = act(A[M,K]bf16 @ W[512,K]bf16^T + b) --
template <int K, int RELU, int OUT_BF16>
__global__ __launch_bounds__(256) void k_fc_mfma(
    const short* __restrict__ A, const short* __restrict__ W,
    const float* __restrict__ bias, void* __restrict__ Cv) {
  const int wv = threadIdx.x >> 6, lane = threadIdx.x & 63;
  const int bm = blockIdx.y * 64;
  const int bn = blockIdx.x * 64 + wv * 16;
  const int cl = lane & 15, quad = lane >> 4;
  const short* ap = A + (size_t)(bm + cl) * K + quad * 8;
  const short* bp = W + (size_t)(bn + cl) * K + quad * 8;
  f32x4 acc0 = {0.f, 0.f, 0.f, 0.f}, acc1 = acc0, acc2 = acc0, acc3 = acc0;
#pragma unroll 4
  for (int k0 = 0; k0 < K; k0 += 32) {
    bf16x8 b = *(const bf16x8*)bp;
    bf16x8 a0 = *(const bf16x8*)ap;
    bf16x8 a1 = *(const bf16x8*)(ap + (size_t)16 * K);
    bf16x8 a2 = *(const bf16x8*)(ap + (size_t)32 * K);
    bf16x8 a3 = *(const bf16x8*)(ap + (size_t)48 * K);
    ap += 32; bp += 32;
    acc0 = __builtin_amdgcn_mfma_f32_16x16x32_bf16(a0, b, acc0, 0, 0, 0);
    acc1 = __builtin_amdgcn_mfma_f32_16x16x32_bf16(a1, b, acc1, 0, 0, 0);
    acc2 = __builtin_amdgcn_mfma_f32_16x16x32_bf16(a2, b, acc2, 0, 0, 0);
    acc3 = __builtin_amdgcn_mfma_f32_16x16x32_bf16(a3, b, acc3, 0, 0, 0);
  }
  const float bia = bias[bn + cl];
  f32x4 av[4] = {acc0, acc1, acc2, acc3};
#pragma unroll
  for (int rt = 0; rt < 4; ++rt) {
#pragma unroll
    for (int r = 0; r < 4; ++r) {
      const int row = bm + rt * 16 + quad * 4 + r;
      float v = av[rt][r] + bia;
      if (RELU) v = fmaxf(v, 0.f);
      if (OUT_BF16)
        ((short*)Cv)[(size_t)row * 512 + bn + cl] = f2bf(v);
      else
        ((float*)Cv)[(size_t)row * 512 + bn + cl] = v;
    }
  }
}

// fc3: one wave per row, N=10, K=512, fp32
__global__ __launch_bounds__(256) void k_fc3(const float* __restrict__ A,
                                             const float* __restrict__ W,
                                             const float* __restrict__ b,
                                             float* __restrict__ out) {
  const int wid = threadIdx.x >> 6, lane = threadIdx.x & 63;
  const int row = blockIdx.x * 4 + wid;
  float p[10];
#pragma unroll
  for (int o = 0; o < 10; ++o) p[o] = 0.f;
  const float* a = A + (size_t)row * 512;
#pragma unroll
  for (int jj = 0; jj < 8; ++jj) {
    const int j = lane + jj * 64;
    float av = a[j];
#pragma unroll
    for (int o = 0; o < 10; ++o) p[o] += av * W[o * 512 + j];
  }
#pragma unroll
  for (int o = 0; o < 10; ++o) p[o] = wave_sum(p[o]);
  if (lane == 0) {
#pragma unroll
    for (int o = 0; o < 10; ++o) out[(size_t)row * 10 + o] = p[o] + b[o];
  }
}

}  // namespace

extern "C" void kernel_launch(void* const* d_in, const int* in_sizes, int n_in,
                              void* d_out, int out_size, void* d_ws,
                              size_t ws_size, hipStream_t stream) {
  const float* x      = (const float*)d_in[0];
  const float* dfe1_w = (const float*)d_in[1];
  const float* dse1_g = (const float*)d_in[2];
  const float* dse1_b = (const float*)d_in[3];
  const float* dse1_w = (const float*)d_in[4];
  const float* bn1_g  = (const float*)d_in[5];
  const float* bn1_b  = (const float*)d_in[6];
  const float* dfe2_w = (const float*)d_in[7];
  const float* dse2_g = (const float*)d_in[8];
  const float* dse2_b = (const float*)d_in[9];
  const float* dse2_w = (const float*)d_in[10];
  const float* bn2_g  = (const float*)d_in[11];
  const float* bn2_b  = (const float*)d_in[12];
  const float* fc1_w  = (const float*)d_in[13];
  const float* fc1_b  = (const float*)d_in[14];
  const float* fc2_w  = (const float*)d_in[15];
  const float* fc2_b  = (const float*)d_in[16];
  const float* fc3_w  = (const float*)d_in[17];
  const float* fc3_b  = (const float*)d_in[18];
  float* out = (float*)d_out;
  char* ws = (char*)d_ws;
  f16* y1 = (f16*)(ws + OFF_Y1);
  f16* y2 = (f16*)(ws + OFF_Y2);
  short* h2 = (short*)(ws + OFF_H2);
  short* a1 = (short*)(ws + OFF_A1);
  float* a2 = (float*)(ws + OFF_A2);
  short* wb1 = (short*)(ws + OFF_WB1);
  short* wb2 = (short*)(ws + OFF_WB2);
  double* st = (double*)(ws + OFF_ST);
  double* ST1 = st;
  double* ST2 = st + (size_t)16 * 8;
  double* ST3 = st + (size_t)32 * 8;
  double* ST4 = st + (size_t)64 * 8;

  k_cast_w<<<1280, 256, 0, stream>>>(fc1_w, fc2_w, wb1, wb2, st);
  k_conv1_y1<<<1024, 256, 0, stream>>>(x, dfe1_w, y1, ST1);
  k_xr1_stats<<<1024, 256, 0, stream>>>(y1, dse1_g, dse1_b, ST1, ST2);
  k_conv2_fused<<<512, 256, 0, stream>>>(y1, dse1_g, dse1_b, dse1_w, bn1_g,
                                         bn1_b, dfe2_w, ST1, ST2, y2, ST3);
  k_xr2_stats<<<512, 256, 0, stream>>>(y2, dse2_g, dse2_b, ST3, ST4);
  k_l2_out<<<1024, 256, 0, stream>>>(y2, dse2_g, dse2_b, dse2_w, bn2_g, bn2_b,
                                     ST3, ST4, h2);
  k_fc_mfma<2048, 1, 1><<<dim3(8, 64), 256, 0, stream>>>(h2, wb1, fc1_b, a1);
  k_fc_mfma<512, 1, 0><<<dim3(8, 64), 256, 0, stream>>>(a1, wb2, fc2_b, a2);
  k_fc3<<<1024, 256, 0, stream>>>(a2, fc3_w, fc3_b, out);
}